// Round 5
// baseline (33.267 us; speedup 1.0000x reference)
//
#include <hip/hip_runtime.h>
#include <math.h>

// Problem constants (fixed by setup_inputs)
#define B_   8
#define S_   512
#define MV_  8        // M_VALID
#define D_   512
#define R_   16
#define MOUT (R_ + 1)            // 17 output slots per (b,s)

typedef float f32x4 __attribute__((ext_vector_type(4)));

// 2048 blocks; block x handles s = x&511 and b in {2*(x>>9), 2*(x>>9)+1}
// (two (b,s) pairs sharing the same s -> same PE row).
// Each thread owns a FIXED d-position d4 = (t&127)*4, so its 4 PE values
// (2 sin/cos pairs) are loop-invariant: computed once into registers.
// No LDS, no barriers. Threads 0-127 (waves 0,1) do even m, threads
// 128-255 (waves 2,3) odd m -> all gather branches wave-uniform.
__global__ __launch_bounds__(256) void block_revert_fused(
    const float* __restrict__ temporal,   // [B][S][MV+1][D]
    const float* __restrict__ mask_token, // [D]
    const float* __restrict__ mod_emb,    // [R+1][D]
    const int*   __restrict__ revert_idx, // [B][S][R]
    float*       __restrict__ out)        // [B][S][MOUT][D]
{
    const int x    = blockIdx.x;          // 0..2047
    const int s    = x & (S_ - 1);
    const int bg   = x >> 9;              // 0..3
    const int t    = threadIdx.x;
    const int half = t >> 7;              // 0/1 (wave-uniform)
    const int d4   = (t & 127) * 4;       // fixed float offset within a row

    // Per-thread PE values (loop-invariant): pairs j0 = d4/2, j0+1.
    const float kNegLn10kOverD = -9.210340371976184f / (float)D_;
    const int j0 = d4 >> 1;               // pair index of first pair
    float f0 = expf((float)(2 * j0)       * kNegLn10kOverD);
    float f1 = expf((float)(2 * (j0 + 1)) * kNegLn10kOverD);
    float s0, c0, s1, c1;
    sincosf((float)s * f0, &s0, &c0);
    sincosf((float)s * f1, &s1, &c1);
    f32x4 p;
    p.x = s0; p.y = c0; p.z = s1; p.w = c1;

    for (int pr = 0; pr < 2; ++pr) {
        const int bs = (bg * 2 + pr) * S_ + s;
        const float* __restrict__ base = temporal + (size_t)bs * ((MV_ + 1) * D_);
        const int*   __restrict__ idxp = revert_idx + bs * R_;
        float*       __restrict__ outb = out + (size_t)bs * (MOUT * D_);

        for (int m = half; m < MOUT; m += 2) {
            const float* src;
            if (m == 0) {
                src = base;                                   // global slot
            } else {
                int idx = idxp[m - 1];                        // wave-uniform broadcast
                src = (idx < MV_) ? (base + (size_t)(1 + idx) * D_)
                                  : mask_token;               // mask fill
            }

            f32x4 v  = *reinterpret_cast<const f32x4*>(src + d4);
            f32x4 me = *reinterpret_cast<const f32x4*>(mod_emb + m * D_ + d4);

            f32x4 o = v + p + me;

            __builtin_nontemporal_store(o,
                reinterpret_cast<f32x4*>(outb + (size_t)m * D_ + d4));
        }
    }
}

extern "C" void kernel_launch(void* const* d_in, const int* in_sizes, int n_in,
                              void* d_out, int out_size, void* d_ws, size_t ws_size,
                              hipStream_t stream) {
    const float* temporal   = (const float*)d_in[0];
    const float* mask_token = (const float*)d_in[1];
    const float* mod_emb    = (const float*)d_in[2];
    const int*   revert_idx = (const int*)d_in[3];
    float*       out        = (float*)d_out;

    block_revert_fused<<<(B_ / 2) * S_, 256, 0, stream>>>(
        temporal, mask_token, mod_emb, revert_idx, out);
}